// Round 7
// baseline (918.145 us; speedup 1.0000x reference)
//
#include <hip/hip_runtime.h>

#define DIV_UP(a,b) (((a)+(b)-1)/(b))

#define CH   9216    // edges per partition block
#define CAP  7424    // max edges per 256-node bucket in sortfill (mean 4096)

// ---------------- CSR build: bucketed counting sort ----------------
// bucket = dst >> 8 (256 nodes per bucket)

__global__ __launch_bounds__(256) void k_hist1(const int* __restrict__ dst, int E,
                                               int NBK, int NB1,
                                               int* __restrict__ blk_hist) {
    __shared__ int hist[512];
    for (int i = threadIdx.x; i < NBK; i += 256) hist[i] = 0;
    __syncthreads();
    int base = blockIdx.x * CH;
    int lim = E - base; if (lim > CH) lim = CH;
    for (int i = threadIdx.x; i < lim; i += 256)
        atomicAdd(&hist[dst[base + i] >> 8], 1);
    __syncthreads();
    for (int b = threadIdx.x; b < NBK; b += 256)
        blk_hist[b * NB1 + blockIdx.x] = hist[b];   // bucket-major
}

__global__ __launch_bounds__(1024) void k_scan1(const int* __restrict__ blk_hist,
                                                int* __restrict__ blk_off,
                                                int* __restrict__ bkt_base,
                                                int NBK, int NB1, int E) {
    __shared__ int part[1024];
    int total = NBK * NB1;
    int chunk = DIV_UP(total, 1024);
    int t = threadIdx.x;
    int lo = t * chunk;
    int hi = lo + chunk; if (hi > total) hi = total;
    int s = 0;
    for (int i = lo; i < hi; i++) s += blk_hist[i];
    part[t] = s;
    __syncthreads();
    for (int o = 1; o < 1024; o <<= 1) {
        int v = (t >= o) ? part[t - o] : 0;
        __syncthreads();
        part[t] += v;
        __syncthreads();
    }
    int run = part[t] - s;   // exclusive prefix of this thread's chunk
    for (int i = lo; i < hi; i++) {
        blk_off[i] = run;
        if (i % NB1 == 0) bkt_base[i / NB1] = run;
        run += blk_hist[i];
    }
    if (t == 0) bkt_base[NBK] = E;
}

__global__ __launch_bounds__(256) void k_scatter1(const int* __restrict__ src,
                                                  const int* __restrict__ dst, int E,
                                                  int NBK, int NB1,
                                                  const int* __restrict__ blk_off,
                                                  unsigned int* __restrict__ part_arr) {
    __shared__ unsigned int   stage[CH];
    __shared__ unsigned short bko[CH];
    __shared__ int hist[512];
    __shared__ int cur[512];
    __shared__ int off[512];

    int t = threadIdx.x;
    hist[t] = 0; hist[t + 256] = 0;
    __syncthreads();

    int base = blockIdx.x * CH;
    int lim = E - base; if (lim > CH) lim = CH;

    for (int i = t; i < lim; i += 256)
        atomicAdd(&hist[dst[base + i] >> 8], 1);
    __syncthreads();

    int c0 = hist[t], c1 = hist[t + 256];
    for (int o = 1; o < 512; o <<= 1) {
        int v0 = (t >= o) ? hist[t - o] : 0;
        int v1 = hist[t + 256 - o];
        __syncthreads();
        hist[t] += v0;
        hist[t + 256] += v1;
        __syncthreads();
    }
    int e0 = hist[t] - c0;          // exclusive
    int e1 = hist[t + 256] - c1;
    cur[t] = e0; cur[t + 256] = e1;
    if (t < NBK)       off[t]       = blk_off[t * NB1 + blockIdx.x] - e0;
    if (t + 256 < NBK) off[t + 256] = blk_off[(t + 256) * NB1 + blockIdx.x] - e1;
    __syncthreads();

    for (int i = t; i < lim; i += 256) {
        int d = dst[base + i];
        int sv = src[base + i];
        int b = d >> 8;
        int slot = atomicAdd(&cur[b], 1);
        stage[slot] = ((unsigned int)sv << 8) | (unsigned int)(d & 255);
        bko[slot] = (unsigned short)b;
    }
    __syncthreads();

    for (int i = t; i < lim; i += 256) {
        int b = bko[i];
        part_arr[off[b] + i] = stage[i];
    }
}

__global__ __launch_bounds__(256) void k_sortfill(const unsigned int* __restrict__ part_arr,
                                                  const int* __restrict__ bkt_base,
                                                  int N, int E,
                                                  int* __restrict__ col,
                                                  int* __restrict__ rowptr,
                                                  float* __restrict__ inv_sqrt) {
    __shared__ unsigned int in_[CAP];
    __shared__ int outS[CAP];
    __shared__ int hist[256];
    __shared__ int scn[256];
    __shared__ int cur[256];

    int b = blockIdx.x;
    int base = bkt_base[b];
    int nb   = bkt_base[b + 1] - base;
    int t = threadIdx.x;

    hist[t] = 0;
    __syncthreads();

    for (int i = t; i < nb; i += 256) {
        unsigned int pk = part_arr[base + i];
        in_[i] = pk;
        atomicAdd(&hist[pk & 255u], 1);
    }
    __syncthreads();

    int cnt = hist[t];
    for (int o = 1; o < 256; o <<= 1) {
        int v = (t >= o) ? hist[t - o] : 0;
        __syncthreads();
        hist[t] += v;
        __syncthreads();
    }
    int excl = hist[t] - cnt;
    scn[t] = excl;
    cur[t] = 0;
    __syncthreads();

    for (int i = t; i < nb; i += 256) {
        unsigned int pk = in_[i];
        int d = (int)(pk & 255u);
        int r = atomicAdd(&cur[d], 1);
        outS[scn[d] + r] = (int)(pk >> 8);
    }
    __syncthreads();

    for (int i = t; i < nb; i += 256) col[base + i] = outS[i];

    int node = b * 256 + t;
    if (node < N) {
        rowptr[node] = base + excl;
        inv_sqrt[node] = rsqrtf((float)(cnt + 1));   // +1: self-loop
    }
    if (b == 0 && t == 0) rowptr[N] = E;
}

// ---------------- Register-tiled GEMM (round-5 known-good) ----------------

__global__ __launch_bounds__(256, 3) void k_gemm_rt(const float* __restrict__ in,
                          const float* __restrict__ W,
                          const float* __restrict__ inv_sqrt,
                          float* __restrict__ out, int N) {
    __shared__ float xsT[32][132];
    __shared__ float ws[32][132];

    const int t = threadIdx.x;
    const int row0 = blockIdx.x * 128;
    const int lane = t & 63;
    const int wave = t >> 6;
    const int rg = ((wave >> 1) << 3) + (lane >> 3);  // 0..15 row group
    const int cg = ((wave & 1) << 3) + (lane & 7);    // 0..15 col group

    const float4* in4 = (const float4*)in;
    const float4* W4  = (const float4*)W;

    float4 acc[8][2];
    #pragma unroll
    for (int i = 0; i < 8; i++) {
        acc[i][0] = make_float4(0.f, 0.f, 0.f, 0.f);
        acc[i][1] = make_float4(0.f, 0.f, 0.f, 0.f);
    }

    const bool full = (row0 + 128 <= N);

    for (int kt = 0; kt < 4; kt++) {
        #pragma unroll
        for (int i = 0; i < 4; i++) {
            int idx = t + i * 256;
            int r  = idx >> 3;
            int c4 = idx & 7;
            int row = row0 + r;
            float4 v = make_float4(0.f, 0.f, 0.f, 0.f);
            if (full || row < N) v = in4[(size_t)row * 32 + kt * 8 + c4];
            xsT[c4 * 4 + 0][r] = v.x;
            xsT[c4 * 4 + 1][r] = v.y;
            xsT[c4 * 4 + 2][r] = v.z;
            xsT[c4 * 4 + 3][r] = v.w;
        }
        #pragma unroll
        for (int i = 0; i < 4; i++) {
            int idx = t + i * 256;
            int kk = idx >> 5;
            int c4 = idx & 31;
            *(float4*)&ws[kk][c4 * 4] = W4[(size_t)(kt * 32 + kk) * 32 + c4];
        }
        __syncthreads();

        #pragma unroll 8
        for (int k = 0; k < 32; k++) {
            float4 a0 = *(const float4*)&xsT[k][rg * 8];
            float4 a1 = *(const float4*)&xsT[k][rg * 8 + 4];
            float4 b0 = *(const float4*)&ws[k][cg * 8];
            float4 b1 = *(const float4*)&ws[k][cg * 8 + 4];
            float av[8] = {a0.x, a0.y, a0.z, a0.w, a1.x, a1.y, a1.z, a1.w};
            #pragma unroll
            for (int i = 0; i < 8; i++) {
                acc[i][0].x += av[i] * b0.x;
                acc[i][0].y += av[i] * b0.y;
                acc[i][0].z += av[i] * b0.z;
                acc[i][0].w += av[i] * b0.w;
                acc[i][1].x += av[i] * b1.x;
                acc[i][1].y += av[i] * b1.y;
                acc[i][1].z += av[i] * b1.z;
                acc[i][1].w += av[i] * b1.w;
            }
        }
        __syncthreads();
    }

    #pragma unroll
    for (int i = 0; i < 8; i++) {
        int row = row0 + rg * 8 + i;
        if (full || row < N) {
            float s = inv_sqrt[row];
            float4 o0 = acc[i][0], o1 = acc[i][1];
            o0.x *= s; o0.y *= s; o0.z *= s; o0.w *= s;
            o1.x *= s; o1.y *= s; o1.z *= s; o1.w *= s;
            float4* o = (float4*)(out + (size_t)row * 128);
            o[cg * 2]     = o0;
            o[cg * 2 + 1] = o1;
        }
    }
}

// ---------------- Aggregate v4: XCD feature-sliced ----------------
// h[n] = relu(inv_sqrt[n]*(sum g[col] + g[n]) + b)
// Block bid handles feature slice (bid&7)*16..+16 of 16 nodes (one per wave).
// With round-robin blockIdx->XCD dispatch, each XCD touches only its
// 6.4 MB column slice of g (vs full 51 MB) -> per-XCD L2-resident.
// Correct regardless of the actual mapping (pure blockIdx partition).
// Wave = 4 edges x 16 features; shfl_xor reduce; 16 gathers in flight.

__global__ __launch_bounds__(1024) void k_agg_slice(const float* __restrict__ g,
                            const int* __restrict__ rowptr,
                            const int* __restrict__ col,
                            const float* __restrict__ inv_sqrt,
                            const float* __restrict__ bias,
                            float* __restrict__ out, int N) {
    int slice = blockIdx.x & 7;
    int grp   = blockIdx.x >> 3;
    int wave  = threadIdx.x >> 6;    // 0..15
    int lane  = threadIdx.x & 63;
    int sub   = lane >> 4;           // 0..3: edge-parallel
    int fl    = lane & 15;           // feature within slice
    int n = grp * 16 + wave;
    if (n >= N) return;

    int fo = slice * 16 + fl;
    const float* gs = g + fo;

    int start = rowptr[n];
    int end   = rowptr[n + 1];

    float acc = 0.f;
    for (int j0 = start; j0 < end; j0 += 16) {
        int   jj[4];
        int   idx[4];
        float v[4];
        #pragma unroll
        for (int u = 0; u < 4; u++) {
            jj[u] = j0 + u * 4 + sub;
            idx[u] = (jj[u] < end) ? col[jj[u]] : n;
        }
        #pragma unroll
        for (int u = 0; u < 4; u++)
            v[u] = gs[(size_t)idx[u] * 128];
        #pragma unroll
        for (int u = 0; u < 4; u++)
            if (jj[u] < end) acc += v[u];
    }

    acc += __shfl_xor(acc, 16);
    acc += __shfl_xor(acc, 32);

    if (sub == 0) {
        float self = gs[(size_t)n * 128];
        float o = fmaxf(inv_sqrt[n] * (acc + self) + bias[fo], 0.f);
        out[(size_t)n * 128 + fo] = o;
    }
}

// ---------------- Pool ----------------

__global__ void k_pool(const float* __restrict__ h, const int* __restrict__ batch,
                       float* __restrict__ pooled, int* __restrict__ counts, int N) {
    int f = threadIdx.x;            // 0..127
    int start = blockIdx.x * 256;
    int end = start + 256; if (end > N) end = N;
    if (start >= N) return;

    int cur = batch[start];
    float acc = 0.f;
    int cnt = 0;
    for (int r = start; r < end; r++) {
        int gi = batch[r];
        if (gi != cur) {
            atomicAdd(&pooled[(size_t)cur * 128 + f], acc);
            if (f == 0) atomicAdd(&counts[cur], cnt);
            acc = 0.f; cnt = 0; cur = gi;
        }
        acc += h[(size_t)r * 128 + f];
        cnt++;
    }
    atomicAdd(&pooled[(size_t)cur * 128 + f], acc);
    if (f == 0) atomicAdd(&counts[cur], cnt);
}

// ---------------- MLP head ----------------

__global__ void k_mlp(const float* __restrict__ pooled, const int* __restrict__ counts,
                      const float* __restrict__ Wc1, const float* __restrict__ bc1,
                      const float* __restrict__ Wc2, const float* __restrict__ bc2,
                      float* __restrict__ out, int G) {
    int g = blockIdx.x;
    int j = threadIdx.x;    // 0..63
    __shared__ float pm[128];
    __shared__ float z[64];

    float invc = 1.0f / fmaxf((float)counts[g], 1.0f);
    pm[j]      = pooled[(size_t)g * 128 + j] * invc;
    pm[j + 64] = pooled[(size_t)g * 128 + 64 + j] * invc;
    __syncthreads();

    float a = bc1[j];
    #pragma unroll 8
    for (int k = 0; k < 128; k++) a += pm[k] * Wc1[k * 64 + j];
    z[j] = fmaxf(a, 0.f);
    __syncthreads();

    if (j < 8) {
        float o = bc2[j];
        #pragma unroll 8
        for (int k = 0; k < 64; k++) o += z[k] * Wc2[k * 8 + j];
        out[(size_t)g * 8 + j] = o;
    }
}

// ---------------- launch ----------------

extern "C" void kernel_launch(void* const* d_in, const int* in_sizes, int n_in,
                              void* d_out, int out_size, void* d_ws, size_t ws_size,
                              hipStream_t stream) {
    const float* x    = (const float*)d_in[0];
    const int*   ei   = (const int*)d_in[1];
    const int*   batch= (const int*)d_in[2];
    const float* W1   = (const float*)d_in[4];
    const float* b1   = (const float*)d_in[5];
    const float* W2   = (const float*)d_in[6];
    const float* b2   = (const float*)d_in[7];
    const float* Wc1  = (const float*)d_in[8];
    const float* bc1  = (const float*)d_in[9];
    const float* Wc2  = (const float*)d_in[10];
    const float* bc2  = (const float*)d_in[11];
    float* out = (float*)d_out;

    const int N = in_sizes[0] / 128;
    const int E = in_sizes[1] / 2;
    const int G = out_size / 8;

    const int* src = ei;
    const int* dst = ei + E;

    const int NBK = DIV_UP(N, 256);     // buckets of 256 nodes
    const int NB1 = DIV_UP(E, CH);      // partition blocks

    char* p = (char*)d_ws;
    auto alloc = [&](size_t bytes) {
        char* q = p;
        p += (bytes + 255) & ~(size_t)255;
        return q;
    };
    float* bufA     = (float*)alloc((size_t)N * 128 * 4);
    float* bufB     = (float*)alloc((size_t)N * 128 * 4);
    int*   rowptr   = (int*)  alloc(((size_t)N + 1) * 4);
    int*   colA     = (int*)  alloc((size_t)E * 4);
    float* inv_sqrt = (float*)alloc((size_t)N * 4);
    int*   blk_hist = (int*)  alloc((size_t)NBK * NB1 * 4);
    int*   blk_off  = (int*)  alloc((size_t)NBK * NB1 * 4);
    int*   bkt_base = (int*)  alloc(((size_t)NBK + 1) * 4);
    float* pooled   = (float*)alloc((size_t)G * 128 * 4);
    int*   counts   = (int*)  alloc((size_t)G * 4);

    // part_arr aliases bufA: consumed by k_sortfill before the first GEMM writes bufA
    unsigned int* part_arr = (unsigned int*)bufA;

    hipMemsetAsync(pooled, 0, (size_t)G * 128 * 4, stream);
    hipMemsetAsync(counts, 0, (size_t)G * 4, stream);

    // CSR build (bucketed counting sort)
    k_hist1<<<NB1, 256, 0, stream>>>(dst, E, NBK, NB1, blk_hist);
    k_scan1<<<1, 1024, 0, stream>>>(blk_hist, blk_off, bkt_base, NBK, NB1, E);
    k_scatter1<<<NB1, 256, 0, stream>>>(src, dst, E, NBK, NB1, blk_off, part_arr);
    k_sortfill<<<NBK, 256, 0, stream>>>(part_arr, bkt_base, N, E, colA, rowptr, inv_sqrt);

    const int aggBlocks = DIV_UP(N, 16) * 8;

    // layer 1
    k_gemm_rt<<<DIV_UP(N, 128), 256, 0, stream>>>(x, W1, inv_sqrt, bufA, N);
    k_agg_slice<<<aggBlocks, 1024, 0, stream>>>(bufA, rowptr, colA, inv_sqrt, b1, bufB, N);

    // layer 2
    k_gemm_rt<<<DIV_UP(N, 128), 256, 0, stream>>>(bufB, W2, inv_sqrt, bufA, N);
    k_agg_slice<<<aggBlocks, 1024, 0, stream>>>(bufA, rowptr, colA, inv_sqrt, b2, bufB, N);

    // pool + head
    k_pool<<<DIV_UP(N, 256), 128, 0, stream>>>(bufB, batch, pooled, counts, N);
    k_mlp<<<G, 64, 0, stream>>>(pooled, counts, Wc1, bc1, Wc2, bc2, out, G);
}

// Round 8
// 489.951 us; speedup vs baseline: 1.8740x; 1.8740x over previous
//
#include <hip/hip_runtime.h>
#include <hip/hip_bf16.h>

#define DIV_UP(a,b) (((a)+(b)-1)/(b))

#define CH   9216    // edges per partition block
#define CAP  7424    // max edges per 256-node bucket in sortfill (mean 4096)

typedef unsigned short ushort_t;
typedef unsigned int   uint_t;

__device__ __forceinline__ ushort_t f2bf(float f) {
    __hip_bfloat16 h = __float2bfloat16(f);   // RNE
    ushort_t u;
    __builtin_memcpy(&u, &h, 2);
    return u;
}

// ---------------- CSR build: bucketed counting sort ----------------
// bucket = dst >> 8 (256 nodes per bucket)

__global__ __launch_bounds__(256) void k_hist1(const int* __restrict__ dst, int E,
                                               int NBK, int NB1,
                                               int* __restrict__ blk_hist) {
    __shared__ int hist[512];
    for (int i = threadIdx.x; i < NBK; i += 256) hist[i] = 0;
    __syncthreads();
    int base = blockIdx.x * CH;
    int lim = E - base; if (lim > CH) lim = CH;
    for (int i = threadIdx.x; i < lim; i += 256)
        atomicAdd(&hist[dst[base + i] >> 8], 1);
    __syncthreads();
    for (int b = threadIdx.x; b < NBK; b += 256)
        blk_hist[b * NB1 + blockIdx.x] = hist[b];   // bucket-major
}

__global__ __launch_bounds__(1024) void k_scan1(const int* __restrict__ blk_hist,
                                                int* __restrict__ blk_off,
                                                int* __restrict__ bkt_base,
                                                int NBK, int NB1, int E) {
    __shared__ int part[1024];
    int total = NBK * NB1;
    int chunk = DIV_UP(total, 1024);
    int t = threadIdx.x;
    int lo = t * chunk;
    int hi = lo + chunk; if (hi > total) hi = total;
    int s = 0;
    for (int i = lo; i < hi; i++) s += blk_hist[i];
    part[t] = s;
    __syncthreads();
    for (int o = 1; o < 1024; o <<= 1) {
        int v = (t >= o) ? part[t - o] : 0;
        __syncthreads();
        part[t] += v;
        __syncthreads();
    }
    int run = part[t] - s;   // exclusive prefix of this thread's chunk
    for (int i = lo; i < hi; i++) {
        blk_off[i] = run;
        if (i % NB1 == 0) bkt_base[i / NB1] = run;
        run += blk_hist[i];
    }
    if (t == 0) bkt_base[NBK] = E;
}

__global__ __launch_bounds__(256) void k_scatter1(const int* __restrict__ src,
                                                  const int* __restrict__ dst, int E,
                                                  int NBK, int NB1,
                                                  const int* __restrict__ blk_off,
                                                  unsigned int* __restrict__ part_arr) {
    __shared__ unsigned int   stage[CH];
    __shared__ unsigned short bko[CH];
    __shared__ int hist[512];
    __shared__ int cur[512];
    __shared__ int off[512];

    int t = threadIdx.x;
    hist[t] = 0; hist[t + 256] = 0;
    __syncthreads();

    int base = blockIdx.x * CH;
    int lim = E - base; if (lim > CH) lim = CH;

    for (int i = t; i < lim; i += 256)
        atomicAdd(&hist[dst[base + i] >> 8], 1);
    __syncthreads();

    int c0 = hist[t], c1 = hist[t + 256];
    for (int o = 1; o < 512; o <<= 1) {
        int v0 = (t >= o) ? hist[t - o] : 0;
        int v1 = hist[t + 256 - o];
        __syncthreads();
        hist[t] += v0;
        hist[t + 256] += v1;
        __syncthreads();
    }
    int e0 = hist[t] - c0;          // exclusive
    int e1 = hist[t + 256] - c1;
    cur[t] = e0; cur[t + 256] = e1;
    if (t < NBK)       off[t]       = blk_off[t * NB1 + blockIdx.x] - e0;
    if (t + 256 < NBK) off[t + 256] = blk_off[(t + 256) * NB1 + blockIdx.x] - e1;
    __syncthreads();

    for (int i = t; i < lim; i += 256) {
        int d = dst[base + i];
        int sv = src[base + i];
        int b = d >> 8;
        int slot = atomicAdd(&cur[b], 1);
        stage[slot] = ((unsigned int)sv << 8) | (unsigned int)(d & 255);
        bko[slot] = (unsigned short)b;
    }
    __syncthreads();

    for (int i = t; i < lim; i += 256) {
        int b = bko[i];
        part_arr[off[b] + i] = stage[i];
    }
}

__global__ __launch_bounds__(256) void k_sortfill(const unsigned int* __restrict__ part_arr,
                                                  const int* __restrict__ bkt_base,
                                                  int N, int E,
                                                  int* __restrict__ col,
                                                  int* __restrict__ rowptr,
                                                  float* __restrict__ inv_sqrt) {
    __shared__ unsigned int in_[CAP];
    __shared__ int outS[CAP];
    __shared__ int hist[256];
    __shared__ int scn[256];
    __shared__ int cur[256];

    int b = blockIdx.x;
    int base = bkt_base[b];
    int nb   = bkt_base[b + 1] - base;
    int t = threadIdx.x;

    hist[t] = 0;
    __syncthreads();

    for (int i = t; i < nb; i += 256) {
        unsigned int pk = part_arr[base + i];
        in_[i] = pk;
        atomicAdd(&hist[pk & 255u], 1);
    }
    __syncthreads();

    int cnt = hist[t];
    for (int o = 1; o < 256; o <<= 1) {
        int v = (t >= o) ? hist[t - o] : 0;
        __syncthreads();
        hist[t] += v;
        __syncthreads();
    }
    int excl = hist[t] - cnt;
    scn[t] = excl;
    cur[t] = 0;
    __syncthreads();

    for (int i = t; i < nb; i += 256) {
        unsigned int pk = in_[i];
        int d = (int)(pk & 255u);
        int r = atomicAdd(&cur[d], 1);
        outS[scn[d] + r] = (int)(pk >> 8);
    }
    __syncthreads();

    for (int i = t; i < nb; i += 256) col[base + i] = outS[i];

    int node = b * 256 + t;
    if (node < N) {
        rowptr[node] = base + excl;
        inv_sqrt[node] = rsqrtf((float)(cnt + 1));   // +1: self-loop
    }
    if (b == 0 && t == 0) rowptr[N] = E;
}

// ---------------- Register-tiled GEMM, bf16 output ----------------
// outg[n][c] = bf16( inv_sqrt[n] * sum_k in[n][k]*W[k][c] )

__global__ __launch_bounds__(256, 3) void k_gemm_rt(const float* __restrict__ in,
                          const float* __restrict__ W,
                          const float* __restrict__ inv_sqrt,
                          ushort_t* __restrict__ outg, int N) {
    __shared__ float xsT[32][132];
    __shared__ float ws[32][132];

    const int t = threadIdx.x;
    const int row0 = blockIdx.x * 128;
    const int lane = t & 63;
    const int wave = t >> 6;
    const int rg = ((wave >> 1) << 3) + (lane >> 3);  // 0..15 row group
    const int cg = ((wave & 1) << 3) + (lane & 7);    // 0..15 col group

    const float4* in4 = (const float4*)in;
    const float4* W4  = (const float4*)W;

    float4 acc[8][2];
    #pragma unroll
    for (int i = 0; i < 8; i++) {
        acc[i][0] = make_float4(0.f, 0.f, 0.f, 0.f);
        acc[i][1] = make_float4(0.f, 0.f, 0.f, 0.f);
    }

    const bool full = (row0 + 128 <= N);

    for (int kt = 0; kt < 4; kt++) {
        #pragma unroll
        for (int i = 0; i < 4; i++) {
            int idx = t + i * 256;
            int r  = idx >> 3;
            int c4 = idx & 7;
            int row = row0 + r;
            float4 v = make_float4(0.f, 0.f, 0.f, 0.f);
            if (full || row < N) v = in4[(size_t)row * 32 + kt * 8 + c4];
            xsT[c4 * 4 + 0][r] = v.x;
            xsT[c4 * 4 + 1][r] = v.y;
            xsT[c4 * 4 + 2][r] = v.z;
            xsT[c4 * 4 + 3][r] = v.w;
        }
        #pragma unroll
        for (int i = 0; i < 4; i++) {
            int idx = t + i * 256;
            int kk = idx >> 5;
            int c4 = idx & 31;
            *(float4*)&ws[kk][c4 * 4] = W4[(size_t)(kt * 32 + kk) * 32 + c4];
        }
        __syncthreads();

        #pragma unroll 8
        for (int k = 0; k < 32; k++) {
            float4 a0 = *(const float4*)&xsT[k][rg * 8];
            float4 a1 = *(const float4*)&xsT[k][rg * 8 + 4];
            float4 b0 = *(const float4*)&ws[k][cg * 8];
            float4 b1 = *(const float4*)&ws[k][cg * 8 + 4];
            float av[8] = {a0.x, a0.y, a0.z, a0.w, a1.x, a1.y, a1.z, a1.w};
            #pragma unroll
            for (int i = 0; i < 8; i++) {
                acc[i][0].x += av[i] * b0.x;
                acc[i][0].y += av[i] * b0.y;
                acc[i][0].z += av[i] * b0.z;
                acc[i][0].w += av[i] * b0.w;
                acc[i][1].x += av[i] * b1.x;
                acc[i][1].y += av[i] * b1.y;
                acc[i][1].z += av[i] * b1.z;
                acc[i][1].w += av[i] * b1.w;
            }
        }
        __syncthreads();
    }

    #pragma unroll
    for (int i = 0; i < 8; i++) {
        int row = row0 + rg * 8 + i;
        if (full || row < N) {
            float s = inv_sqrt[row];
            float4 o0 = acc[i][0], o1 = acc[i][1];
            uint4 pk;
            pk.x = (uint_t)f2bf(s * o0.x) | ((uint_t)f2bf(s * o0.y) << 16);
            pk.y = (uint_t)f2bf(s * o0.z) | ((uint_t)f2bf(s * o0.w) << 16);
            pk.z = (uint_t)f2bf(s * o1.x) | ((uint_t)f2bf(s * o1.y) << 16);
            pk.w = (uint_t)f2bf(s * o1.z) | ((uint_t)f2bf(s * o1.w) << 16);
            ((uint4*)(outg + (size_t)row * 128))[cg] = pk;
        }
    }
}

// ---------------- Aggregate (v2 structure, bf16 gather) ----------------
// h[n] = relu(inv_sqrt[n]*(sum_{e in CSR[n]} g[col[e]] + g[n]) + b)
// one wave per node; lane holds 2 features as packed bf16 (uint), f32 accum.
// Unrolled x8 with predicated dummy loads (self row, cache-hot).

__global__ __launch_bounds__(256) void k_aggregate(const ushort_t* __restrict__ g,
                            const int* __restrict__ rowptr,
                            const int* __restrict__ col, const float* __restrict__ inv_sqrt,
                            const float* __restrict__ bias, float* __restrict__ out, int N) {
    int wid  = (blockIdx.x * blockDim.x + threadIdx.x) >> 6;   // node
    int lane = threadIdx.x & 63;
    if (wid >= N) return;

    int start = rowptr[wid];
    int end   = rowptr[wid + 1];

    const uint_t* g1 = (const uint_t*)g;    // row = 64 uints (128 bf16)
    float accx = 0.f, accy = 0.f;

    for (int tt = start; tt < end; tt += 8) {
        int idx[8];
        #pragma unroll
        for (int i = 0; i < 8; i++)
            idx[i] = (tt + i < end) ? col[tt + i] : wid;
        uint_t v[8];
        #pragma unroll
        for (int i = 0; i < 8; i++)
            v[i] = g1[(size_t)((unsigned)idx[i] * 64u + (unsigned)lane)];
        #pragma unroll
        for (int i = 0; i < 8; i++) {
            if (tt + i < end) {
                accx += __uint_as_float(v[i] << 16);
                accy += __uint_as_float(v[i] & 0xffff0000u);
            }
        }
    }

    uint_t sv = g1[(unsigned)wid * 64u + (unsigned)lane];
    accx += __uint_as_float(sv << 16);
    accy += __uint_as_float(sv & 0xffff0000u);

    float is = inv_sqrt[wid];
    float2 b = ((const float2*)bias)[lane];
    float ox = fmaxf(fmaf(is, accx, b.x), 0.f);
    float oy = fmaxf(fmaf(is, accy, b.y), 0.f);
    ((float2*)(out + (size_t)wid * 128))[lane] = make_float2(ox, oy);
}

// ---------------- Pool ----------------

__global__ void k_pool(const float* __restrict__ h, const int* __restrict__ batch,
                       float* __restrict__ pooled, int* __restrict__ counts, int N) {
    int f = threadIdx.x;            // 0..127
    int start = blockIdx.x * 256;
    int end = start + 256; if (end > N) end = N;
    if (start >= N) return;

    int cur = batch[start];
    float acc = 0.f;
    int cnt = 0;
    for (int r = start; r < end; r++) {
        int gi = batch[r];
        if (gi != cur) {
            atomicAdd(&pooled[(size_t)cur * 128 + f], acc);
            if (f == 0) atomicAdd(&counts[cur], cnt);
            acc = 0.f; cnt = 0; cur = gi;
        }
        acc += h[(size_t)r * 128 + f];
        cnt++;
    }
    atomicAdd(&pooled[(size_t)cur * 128 + f], acc);
    if (f == 0) atomicAdd(&counts[cur], cnt);
}

// ---------------- MLP head ----------------

__global__ void k_mlp(const float* __restrict__ pooled, const int* __restrict__ counts,
                      const float* __restrict__ Wc1, const float* __restrict__ bc1,
                      const float* __restrict__ Wc2, const float* __restrict__ bc2,
                      float* __restrict__ out, int G) {
    int g = blockIdx.x;
    int j = threadIdx.x;    // 0..63
    __shared__ float pm[128];
    __shared__ float z[64];

    float invc = 1.0f / fmaxf((float)counts[g], 1.0f);
    pm[j]      = pooled[(size_t)g * 128 + j] * invc;
    pm[j + 64] = pooled[(size_t)g * 128 + 64 + j] * invc;
    __syncthreads();

    float a = bc1[j];
    #pragma unroll 8
    for (int k = 0; k < 128; k++) a += pm[k] * Wc1[k * 64 + j];
    z[j] = fmaxf(a, 0.f);
    __syncthreads();

    if (j < 8) {
        float o = bc2[j];
        #pragma unroll 8
        for (int k = 0; k < 64; k++) o += z[k] * Wc2[k * 8 + j];
        out[(size_t)g * 8 + j] = o;
    }
}

// ---------------- launch ----------------

extern "C" void kernel_launch(void* const* d_in, const int* in_sizes, int n_in,
                              void* d_out, int out_size, void* d_ws, size_t ws_size,
                              hipStream_t stream) {
    const float* x    = (const float*)d_in[0];
    const int*   ei   = (const int*)d_in[1];
    const int*   batch= (const int*)d_in[2];
    const float* W1   = (const float*)d_in[4];
    const float* b1   = (const float*)d_in[5];
    const float* W2   = (const float*)d_in[6];
    const float* b2   = (const float*)d_in[7];
    const float* Wc1  = (const float*)d_in[8];
    const float* bc1  = (const float*)d_in[9];
    const float* Wc2  = (const float*)d_in[10];
    const float* bc2  = (const float*)d_in[11];
    float* out = (float*)d_out;

    const int N = in_sizes[0] / 128;
    const int E = in_sizes[1] / 2;
    const int G = out_size / 8;

    const int* src = ei;
    const int* dst = ei + E;

    const int NBK = DIV_UP(N, 256);     // buckets of 256 nodes
    const int NB1 = DIV_UP(E, CH);      // partition blocks

    char* p = (char*)d_ws;
    auto alloc = [&](size_t bytes) {
        char* q = p;
        p += (bytes + 255) & ~(size_t)255;
        return q;
    };
    float*    bufB     = (float*)   alloc((size_t)N * 128 * 4);  // h (f32)
    ushort_t* bufG     = (ushort_t*)alloc((size_t)N * 128 * 2);  // g (bf16)
    int*      rowptr   = (int*)     alloc(((size_t)N + 1) * 4);
    int*      colA     = (int*)     alloc((size_t)E * 4);
    float*    inv_sqrt = (float*)   alloc((size_t)N * 4);
    int*      blk_hist = (int*)     alloc((size_t)NBK * NB1 * 4);
    int*      blk_off  = (int*)     alloc((size_t)NBK * NB1 * 4);
    int*      bkt_base = (int*)     alloc(((size_t)NBK + 1) * 4);
    float*    pooled   = (float*)   alloc((size_t)G * 128 * 4);
    int*      counts   = (int*)     alloc((size_t)G * 4);

    // part_arr aliases bufG: consumed by k_sortfill before GEMM1 writes bufG
    unsigned int* part_arr = (unsigned int*)bufG;

    hipMemsetAsync(pooled, 0, (size_t)G * 128 * 4, stream);
    hipMemsetAsync(counts, 0, (size_t)G * 4, stream);

    // CSR build (bucketed counting sort)
    k_hist1<<<NB1, 256, 0, stream>>>(dst, E, NBK, NB1, blk_hist);
    k_scan1<<<1, 1024, 0, stream>>>(blk_hist, blk_off, bkt_base, NBK, NB1, E);
    k_scatter1<<<NB1, 256, 0, stream>>>(src, dst, E, NBK, NB1, blk_off, part_arr);
    k_sortfill<<<NBK, 256, 0, stream>>>(part_arr, bkt_base, N, E, colA, rowptr, inv_sqrt);

    // layer 1
    k_gemm_rt<<<DIV_UP(N, 128), 256, 0, stream>>>(x, W1, inv_sqrt, bufG, N);
    k_aggregate<<<DIV_UP(N, 4), 256, 0, stream>>>(bufG, rowptr, colA, inv_sqrt, b1, bufB, N);

    // layer 2
    k_gemm_rt<<<DIV_UP(N, 128), 256, 0, stream>>>(bufB, W2, inv_sqrt, bufG, N);
    k_aggregate<<<DIV_UP(N, 4), 256, 0, stream>>>(bufG, rowptr, colA, inv_sqrt, b2, bufB, N);

    // pool + head
    k_pool<<<DIV_UP(N, 256), 128, 0, stream>>>(bufB, batch, pooled, counts, N);
    k_mlp<<<G, 64, 0, stream>>>(pooled, counts, Wc1, bc1, Wc2, bc2, out, G);
}

// Round 9
// 387.631 us; speedup vs baseline: 2.3686x; 1.2640x over previous
//
#include <hip/hip_runtime.h>
#include <hip/hip_bf16.h>

#define DIV_UP(a,b) (((a)+(b)-1)/(b))

#define CH   9216    // edges per partition block
#define CAP  7424    // max edges per 256-node bucket in sortfill (mean 4096)

typedef unsigned short ushort_t;
typedef unsigned int   uint_t;

__device__ __forceinline__ ushort_t f2bf(float f) {
    __hip_bfloat16 h = __float2bfloat16(f);   // RNE
    ushort_t u;
    __builtin_memcpy(&u, &h, 2);
    return u;
}

// ---------------- CSR build: bucketed counting sort ----------------
// bucket = dst >> 8 (256 nodes per bucket)

__global__ __launch_bounds__(256) void k_hist1(const int* __restrict__ dst, int E,
                                               int NBK, int NB1,
                                               int* __restrict__ blk_hist) {
    __shared__ int hist[512];
    for (int i = threadIdx.x; i < NBK; i += 256) hist[i] = 0;
    __syncthreads();
    int base = blockIdx.x * CH;
    int lim = E - base; if (lim > CH) lim = CH;
    for (int i = threadIdx.x; i < lim; i += 256)
        atomicAdd(&hist[dst[base + i] >> 8], 1);
    __syncthreads();
    for (int b = threadIdx.x; b < NBK; b += 256)
        blk_hist[b * NB1 + blockIdx.x] = hist[b];   // bucket-major
}

// ---- parallel scan, level 1: per-bucket row scan + bucket totals ----
__global__ __launch_bounds__(256) void k_rowscan(const int* __restrict__ blk_hist,
                                                 int* __restrict__ blk_off,
                                                 int* __restrict__ T,
                                                 int NB1) {
    __shared__ int s[256];
    int b = blockIdx.x;
    const int* row = blk_hist + (size_t)b * NB1;
    int* orow = blk_off + (size_t)b * NB1;
    int t = threadIdx.x;
    int K = DIV_UP(NB1, 256);
    int lo = t * K;
    int hi = lo + K; if (hi > NB1) hi = NB1;
    int sum = 0;
    for (int i = lo; i < hi; i++) sum += row[i];
    s[t] = sum;
    __syncthreads();
    for (int o = 1; o < 256; o <<= 1) {
        int v = (t >= o) ? s[t - o] : 0;
        __syncthreads();
        s[t] += v;
        __syncthreads();
    }
    int run = s[t] - sum;   // exclusive prefix of this thread's chunk
    for (int i = lo; i < hi; i++) { orow[i] = run; run += row[i]; }
    if (t == 255) T[b] = s[255];
}

// ---- parallel scan, level 2: scan of bucket totals (tiny) ----
__global__ __launch_bounds__(1024) void k_bktscan(const int* __restrict__ T,
                                                  int* __restrict__ bkt_base,
                                                  int NBK, int E) {
    __shared__ int s[1024];
    int t = threadIdx.x;
    int K = DIV_UP(NBK, 1024);
    int lo = t * K;
    int hi = lo + K; if (hi > NBK) hi = NBK;
    int sum = 0;
    for (int i = lo; i < hi; i++) sum += T[i];
    s[t] = sum;
    __syncthreads();
    for (int o = 1; o < 1024; o <<= 1) {
        int v = (t >= o) ? s[t - o] : 0;
        __syncthreads();
        s[t] += v;
        __syncthreads();
    }
    int run = s[t] - sum;
    for (int i = lo; i < hi; i++) { bkt_base[i] = run; run += T[i]; }
    if (t == 0) bkt_base[NBK] = E;
}

// ---- parallel scan, level 3: add bucket base to each row ----
__global__ __launch_bounds__(256) void k_addbase(int* __restrict__ blk_off,
                                                 const int* __restrict__ bkt_base,
                                                 int NB1) {
    int b = blockIdx.x;
    int base = bkt_base[b];
    int* orow = blk_off + (size_t)b * NB1;
    for (int i = threadIdx.x; i < NB1; i += 256) orow[i] += base;
}

__global__ __launch_bounds__(256) void k_scatter1(const int* __restrict__ src,
                                                  const int* __restrict__ dst, int E,
                                                  int NBK, int NB1,
                                                  const int* __restrict__ blk_off,
                                                  unsigned int* __restrict__ part_arr) {
    __shared__ unsigned int   stage[CH];
    __shared__ unsigned short bko[CH];
    __shared__ int hist[512];
    __shared__ int cur[512];
    __shared__ int off[512];

    int t = threadIdx.x;
    hist[t] = 0; hist[t + 256] = 0;
    __syncthreads();

    int base = blockIdx.x * CH;
    int lim = E - base; if (lim > CH) lim = CH;

    for (int i = t; i < lim; i += 256)
        atomicAdd(&hist[dst[base + i] >> 8], 1);
    __syncthreads();

    int c0 = hist[t], c1 = hist[t + 256];
    for (int o = 1; o < 512; o <<= 1) {
        int v0 = (t >= o) ? hist[t - o] : 0;
        int v1 = hist[t + 256 - o];
        __syncthreads();
        hist[t] += v0;
        hist[t + 256] += v1;
        __syncthreads();
    }
    int e0 = hist[t] - c0;          // exclusive
    int e1 = hist[t + 256] - c1;
    cur[t] = e0; cur[t + 256] = e1;
    if (t < NBK)       off[t]       = blk_off[t * NB1 + blockIdx.x] - e0;
    if (t + 256 < NBK) off[t + 256] = blk_off[(t + 256) * NB1 + blockIdx.x] - e1;
    __syncthreads();

    for (int i = t; i < lim; i += 256) {
        int d = dst[base + i];
        int sv = src[base + i];
        int b = d >> 8;
        int slot = atomicAdd(&cur[b], 1);
        stage[slot] = ((unsigned int)sv << 8) | (unsigned int)(d & 255);
        bko[slot] = (unsigned short)b;
    }
    __syncthreads();

    for (int i = t; i < lim; i += 256) {
        int b = bko[i];
        part_arr[off[b] + i] = stage[i];
    }
}

__global__ __launch_bounds__(256) void k_sortfill(const unsigned int* __restrict__ part_arr,
                                                  const int* __restrict__ bkt_base,
                                                  int N, int E,
                                                  int* __restrict__ col,
                                                  int* __restrict__ rowptr,
                                                  float* __restrict__ inv_sqrt) {
    __shared__ unsigned int in_[CAP];
    __shared__ int outS[CAP];
    __shared__ int hist[256];
    __shared__ int scn[256];
    __shared__ int cur[256];

    int b = blockIdx.x;
    int base = bkt_base[b];
    int nb   = bkt_base[b + 1] - base;
    int t = threadIdx.x;

    hist[t] = 0;
    __syncthreads();

    for (int i = t; i < nb; i += 256) {
        unsigned int pk = part_arr[base + i];
        in_[i] = pk;
        atomicAdd(&hist[pk & 255u], 1);
    }
    __syncthreads();

    int cnt = hist[t];
    for (int o = 1; o < 256; o <<= 1) {
        int v = (t >= o) ? hist[t - o] : 0;
        __syncthreads();
        hist[t] += v;
        __syncthreads();
    }
    int excl = hist[t] - cnt;
    scn[t] = excl;
    cur[t] = 0;
    __syncthreads();

    for (int i = t; i < nb; i += 256) {
        unsigned int pk = in_[i];
        int d = (int)(pk & 255u);
        int r = atomicAdd(&cur[d], 1);
        outS[scn[d] + r] = (int)(pk >> 8);
    }
    __syncthreads();

    for (int i = t; i < nb; i += 256) col[base + i] = outS[i];

    int node = b * 256 + t;
    if (node < N) {
        rowptr[node] = base + excl;
        inv_sqrt[node] = rsqrtf((float)(cnt + 1));   // +1: self-loop
    }
    if (b == 0 && t == 0) rowptr[N] = E;
}

// ---------------- Register-tiled GEMM, bf16 output ----------------

__global__ __launch_bounds__(256, 3) void k_gemm_rt(const float* __restrict__ in,
                          const float* __restrict__ W,
                          const float* __restrict__ inv_sqrt,
                          ushort_t* __restrict__ outg, int N) {
    __shared__ float xsT[32][132];
    __shared__ float ws[32][132];

    const int t = threadIdx.x;
    const int row0 = blockIdx.x * 128;
    const int lane = t & 63;
    const int wave = t >> 6;
    const int rg = ((wave >> 1) << 3) + (lane >> 3);  // 0..15 row group
    const int cg = ((wave & 1) << 3) + (lane & 7);    // 0..15 col group

    const float4* in4 = (const float4*)in;
    const float4* W4  = (const float4*)W;

    float4 acc[8][2];
    #pragma unroll
    for (int i = 0; i < 8; i++) {
        acc[i][0] = make_float4(0.f, 0.f, 0.f, 0.f);
        acc[i][1] = make_float4(0.f, 0.f, 0.f, 0.f);
    }

    const bool full = (row0 + 128 <= N);

    for (int kt = 0; kt < 4; kt++) {
        #pragma unroll
        for (int i = 0; i < 4; i++) {
            int idx = t + i * 256;
            int r  = idx >> 3;
            int c4 = idx & 7;
            int row = row0 + r;
            float4 v = make_float4(0.f, 0.f, 0.f, 0.f);
            if (full || row < N) v = in4[(size_t)row * 32 + kt * 8 + c4];
            xsT[c4 * 4 + 0][r] = v.x;
            xsT[c4 * 4 + 1][r] = v.y;
            xsT[c4 * 4 + 2][r] = v.z;
            xsT[c4 * 4 + 3][r] = v.w;
        }
        #pragma unroll
        for (int i = 0; i < 4; i++) {
            int idx = t + i * 256;
            int kk = idx >> 5;
            int c4 = idx & 31;
            *(float4*)&ws[kk][c4 * 4] = W4[(size_t)(kt * 32 + kk) * 32 + c4];
        }
        __syncthreads();

        #pragma unroll 8
        for (int k = 0; k < 32; k++) {
            float4 a0 = *(const float4*)&xsT[k][rg * 8];
            float4 a1 = *(const float4*)&xsT[k][rg * 8 + 4];
            float4 b0 = *(const float4*)&ws[k][cg * 8];
            float4 b1 = *(const float4*)&ws[k][cg * 8 + 4];
            float av[8] = {a0.x, a0.y, a0.z, a0.w, a1.x, a1.y, a1.z, a1.w};
            #pragma unroll
            for (int i = 0; i < 8; i++) {
                acc[i][0].x += av[i] * b0.x;
                acc[i][0].y += av[i] * b0.y;
                acc[i][0].z += av[i] * b0.z;
                acc[i][0].w += av[i] * b0.w;
                acc[i][1].x += av[i] * b1.x;
                acc[i][1].y += av[i] * b1.y;
                acc[i][1].z += av[i] * b1.z;
                acc[i][1].w += av[i] * b1.w;
            }
        }
        __syncthreads();
    }

    #pragma unroll
    for (int i = 0; i < 8; i++) {
        int row = row0 + rg * 8 + i;
        if (full || row < N) {
            float s = inv_sqrt[row];
            float4 o0 = acc[i][0], o1 = acc[i][1];
            uint4 pk;
            pk.x = (uint_t)f2bf(s * o0.x) | ((uint_t)f2bf(s * o0.y) << 16);
            pk.y = (uint_t)f2bf(s * o0.z) | ((uint_t)f2bf(s * o0.w) << 16);
            pk.z = (uint_t)f2bf(s * o1.x) | ((uint_t)f2bf(s * o1.y) << 16);
            pk.w = (uint_t)f2bf(s * o1.z) | ((uint_t)f2bf(s * o1.w) << 16);
            ((uint4*)(outg + (size_t)row * 128))[cg] = pk;
        }
    }
}

// ---------------- Aggregate (bf16 gather) ----------------

__global__ __launch_bounds__(256) void k_aggregate(const ushort_t* __restrict__ g,
                            const int* __restrict__ rowptr,
                            const int* __restrict__ col, const float* __restrict__ inv_sqrt,
                            const float* __restrict__ bias, float* __restrict__ out, int N) {
    int wid  = (blockIdx.x * blockDim.x + threadIdx.x) >> 6;   // node
    int lane = threadIdx.x & 63;
    if (wid >= N) return;

    int start = rowptr[wid];
    int end   = rowptr[wid + 1];

    const uint_t* g1 = (const uint_t*)g;    // row = 64 uints (128 bf16)
    float accx = 0.f, accy = 0.f;

    for (int tt = start; tt < end; tt += 8) {
        int idx[8];
        #pragma unroll
        for (int i = 0; i < 8; i++)
            idx[i] = (tt + i < end) ? col[tt + i] : wid;
        uint_t v[8];
        #pragma unroll
        for (int i = 0; i < 8; i++)
            v[i] = g1[(size_t)((unsigned)idx[i] * 64u + (unsigned)lane)];
        #pragma unroll
        for (int i = 0; i < 8; i++) {
            if (tt + i < end) {
                accx += __uint_as_float(v[i] << 16);
                accy += __uint_as_float(v[i] & 0xffff0000u);
            }
        }
    }

    uint_t sv = g1[(unsigned)wid * 64u + (unsigned)lane];
    accx += __uint_as_float(sv << 16);
    accy += __uint_as_float(sv & 0xffff0000u);

    float is = inv_sqrt[wid];
    float2 b = ((const float2*)bias)[lane];
    float ox = fmaxf(fmaf(is, accx, b.x), 0.f);
    float oy = fmaxf(fmaf(is, accy, b.y), 0.f);
    ((float2*)(out + (size_t)wid * 128))[lane] = make_float2(ox, oy);
}

// ---------------- Pool ----------------

__global__ void k_pool(const float* __restrict__ h, const int* __restrict__ batch,
                       float* __restrict__ pooled, int* __restrict__ counts, int N) {
    int f = threadIdx.x;            // 0..127
    int start = blockIdx.x * 256;
    int end = start + 256; if (end > N) end = N;
    if (start >= N) return;

    int cur = batch[start];
    float acc = 0.f;
    int cnt = 0;
    for (int r = start; r < end; r++) {
        int gi = batch[r];
        if (gi != cur) {
            atomicAdd(&pooled[(size_t)cur * 128 + f], acc);
            if (f == 0) atomicAdd(&counts[cur], cnt);
            acc = 0.f; cnt = 0; cur = gi;
        }
        acc += h[(size_t)r * 128 + f];
        cnt++;
    }
    atomicAdd(&pooled[(size_t)cur * 128 + f], acc);
    if (f == 0) atomicAdd(&counts[cur], cnt);
}

// ---------------- MLP head ----------------

__global__ void k_mlp(const float* __restrict__ pooled, const int* __restrict__ counts,
                      const float* __restrict__ Wc1, const float* __restrict__ bc1,
                      const float* __restrict__ Wc2, const float* __restrict__ bc2,
                      float* __restrict__ out, int G) {
    int g = blockIdx.x;
    int j = threadIdx.x;    // 0..63
    __shared__ float pm[128];
    __shared__ float z[64];

    float invc = 1.0f / fmaxf((float)counts[g], 1.0f);
    pm[j]      = pooled[(size_t)g * 128 + j] * invc;
    pm[j + 64] = pooled[(size_t)g * 128 + 64 + j] * invc;
    __syncthreads();

    float a = bc1[j];
    #pragma unroll 8
    for (int k = 0; k < 128; k++) a += pm[k] * Wc1[k * 64 + j];
    z[j] = fmaxf(a, 0.f);
    __syncthreads();

    if (j < 8) {
        float o = bc2[j];
        #pragma unroll 8
        for (int k = 0; k < 64; k++) o += z[k] * Wc2[k * 8 + j];
        out[(size_t)g * 8 + j] = o;
    }
}

// ---------------- launch ----------------

extern "C" void kernel_launch(void* const* d_in, const int* in_sizes, int n_in,
                              void* d_out, int out_size, void* d_ws, size_t ws_size,
                              hipStream_t stream) {
    const float* x    = (const float*)d_in[0];
    const int*   ei   = (const int*)d_in[1];
    const int*   batch= (const int*)d_in[2];
    const float* W1   = (const float*)d_in[4];
    const float* b1   = (const float*)d_in[5];
    const float* W2   = (const float*)d_in[6];
    const float* b2   = (const float*)d_in[7];
    const float* Wc1  = (const float*)d_in[8];
    const float* bc1  = (const float*)d_in[9];
    const float* Wc2  = (const float*)d_in[10];
    const float* bc2  = (const float*)d_in[11];
    float* out = (float*)d_out;

    const int N = in_sizes[0] / 128;
    const int E = in_sizes[1] / 2;
    const int G = out_size / 8;

    const int* src = ei;
    const int* dst = ei + E;

    const int NBK = DIV_UP(N, 256);     // buckets of 256 nodes
    const int NB1 = DIV_UP(E, CH);      // partition blocks

    char* p = (char*)d_ws;
    auto alloc = [&](size_t bytes) {
        char* q = p;
        p += (bytes + 255) & ~(size_t)255;
        return q;
    };
    float*    bufB     = (float*)   alloc((size_t)N * 128 * 4);  // h (f32)
    ushort_t* bufG     = (ushort_t*)alloc((size_t)N * 128 * 2);  // g (bf16)
    int*      rowptr   = (int*)     alloc(((size_t)N + 1) * 4);
    int*      colA     = (int*)     alloc((size_t)E * 4);
    float*    inv_sqrt = (float*)   alloc((size_t)N * 4);
    int*      blk_hist = (int*)     alloc((size_t)NBK * NB1 * 4);
    int*      blk_off  = (int*)     alloc((size_t)NBK * NB1 * 4);
    int*      bkt_base = (int*)     alloc(((size_t)NBK + 1) * 4);
    int*      bktT     = (int*)     alloc((size_t)NBK * 4);
    float*    pooled   = (float*)   alloc((size_t)G * 128 * 4);
    int*      counts   = (int*)     alloc((size_t)G * 4);

    // part_arr aliases bufG: consumed by k_sortfill before GEMM1 writes bufG
    unsigned int* part_arr = (unsigned int*)bufG;

    hipMemsetAsync(pooled, 0, (size_t)G * 128 * 4, stream);
    hipMemsetAsync(counts, 0, (size_t)G * 4, stream);

    // CSR build (bucketed counting sort, parallel 3-level scan)
    k_hist1<<<NB1, 256, 0, stream>>>(dst, E, NBK, NB1, blk_hist);
    k_rowscan<<<NBK, 256, 0, stream>>>(blk_hist, blk_off, bktT, NB1);
    k_bktscan<<<1, 1024, 0, stream>>>(bktT, bkt_base, NBK, E);
    k_addbase<<<NBK, 256, 0, stream>>>(blk_off, bkt_base, NB1);
    k_scatter1<<<NB1, 256, 0, stream>>>(src, dst, E, NBK, NB1, blk_off, part_arr);
    k_sortfill<<<NBK, 256, 0, stream>>>(part_arr, bkt_base, N, E, colA, rowptr, inv_sqrt);

    // layer 1
    k_gemm_rt<<<DIV_UP(N, 128), 256, 0, stream>>>(x, W1, inv_sqrt, bufG, N);
    k_aggregate<<<DIV_UP(N, 4), 256, 0, stream>>>(bufG, rowptr, colA, inv_sqrt, b1, bufB, N);

    // layer 2
    k_gemm_rt<<<DIV_UP(N, 128), 256, 0, stream>>>(bufB, W2, inv_sqrt, bufG, N);
    k_aggregate<<<DIV_UP(N, 4), 256, 0, stream>>>(bufG, rowptr, colA, inv_sqrt, b2, bufB, N);

    // pool + head
    k_pool<<<DIV_UP(N, 256), 128, 0, stream>>>(bufB, batch, pooled, counts, N);
    k_mlp<<<G, 64, 0, stream>>>(pooled, counts, Wc1, bc1, Wc2, bc2, out, G);
}

// Round 10
// 341.685 us; speedup vs baseline: 2.6871x; 1.1345x over previous
//
#include <hip/hip_runtime.h>
#include <hip/hip_bf16.h>

#define DIV_UP(a,b) (((a)+(b)-1)/(b))

#define CH   9216    // edges per partition block
#define CAP  7424    // max edges per 256-node bucket in sortfill (mean 4096)

typedef unsigned short ushort_t;
typedef unsigned int   uint_t;

__device__ __forceinline__ ushort_t f2bf(float f) {
    __hip_bfloat16 h = __float2bfloat16(f);   // RNE
    ushort_t u;
    __builtin_memcpy(&u, &h, 2);
    return u;
}
__device__ __forceinline__ float bfl(uint_t u) { return __uint_as_float(u << 16); }
__device__ __forceinline__ float bfh(uint_t u) { return __uint_as_float(u & 0xffff0000u); }

// ---------------- CSR build: bucketed counting sort ----------------
// bucket = dst >> 8 (256 nodes per bucket)

__global__ __launch_bounds__(256) void k_hist1(const int* __restrict__ dst, int E,
                                               int NBK, int NB1,
                                               int* __restrict__ blk_hist) {
    __shared__ int hist[512];
    for (int i = threadIdx.x; i < NBK; i += 256) hist[i] = 0;
    __syncthreads();
    int base = blockIdx.x * CH;
    int lim = E - base; if (lim > CH) lim = CH;
    for (int i = threadIdx.x; i < lim; i += 256)
        atomicAdd(&hist[dst[base + i] >> 8], 1);
    __syncthreads();
    for (int b = threadIdx.x; b < NBK; b += 256)
        blk_hist[b * NB1 + blockIdx.x] = hist[b];   // bucket-major
}

// ---- parallel scan, level 1: per-bucket row scan + bucket totals ----
__global__ __launch_bounds__(256) void k_rowscan(const int* __restrict__ blk_hist,
                                                 int* __restrict__ blk_off,
                                                 int* __restrict__ T,
                                                 int NB1) {
    __shared__ int s[256];
    int b = blockIdx.x;
    const int* row = blk_hist + (size_t)b * NB1;
    int* orow = blk_off + (size_t)b * NB1;
    int t = threadIdx.x;
    int K = DIV_UP(NB1, 256);
    int lo = t * K;
    int hi = lo + K; if (hi > NB1) hi = NB1;
    int sum = 0;
    for (int i = lo; i < hi; i++) sum += row[i];
    s[t] = sum;
    __syncthreads();
    for (int o = 1; o < 256; o <<= 1) {
        int v = (t >= o) ? s[t - o] : 0;
        __syncthreads();
        s[t] += v;
        __syncthreads();
    }
    int run = s[t] - sum;   // exclusive prefix of this thread's chunk
    for (int i = lo; i < hi; i++) { orow[i] = run; run += row[i]; }
    if (t == 255) T[b] = s[255];
}

// ---- parallel scan, level 2: scan of bucket totals (tiny) ----
__global__ __launch_bounds__(1024) void k_bktscan(const int* __restrict__ T,
                                                  int* __restrict__ bkt_base,
                                                  int NBK, int E) {
    __shared__ int s[1024];
    int t = threadIdx.x;
    int K = DIV_UP(NBK, 1024);
    int lo = t * K;
    int hi = lo + K; if (hi > NBK) hi = NBK;
    int sum = 0;
    for (int i = lo; i < hi; i++) sum += T[i];
    s[t] = sum;
    __syncthreads();
    for (int o = 1; o < 1024; o <<= 1) {
        int v = (t >= o) ? s[t - o] : 0;
        __syncthreads();
        s[t] += v;
        __syncthreads();
    }
    int run = s[t] - sum;
    for (int i = lo; i < hi; i++) { bkt_base[i] = run; run += T[i]; }
    if (t == 0) bkt_base[NBK] = E;
}

// ---- parallel scan, level 3: add bucket base to each row ----
__global__ __launch_bounds__(256) void k_addbase(int* __restrict__ blk_off,
                                                 const int* __restrict__ bkt_base,
                                                 int NB1) {
    int b = blockIdx.x;
    int base = bkt_base[b];
    int* orow = blk_off + (size_t)b * NB1;
    for (int i = threadIdx.x; i < NB1; i += 256) orow[i] += base;
}

__global__ __launch_bounds__(256) void k_scatter1(const int* __restrict__ src,
                                                  const int* __restrict__ dst, int E,
                                                  int NBK, int NB1,
                                                  const int* __restrict__ blk_off,
                                                  unsigned int* __restrict__ part_arr) {
    __shared__ unsigned int   stage[CH];
    __shared__ unsigned short bko[CH];
    __shared__ int hist[512];
    __shared__ int cur[512];
    __shared__ int off[512];

    int t = threadIdx.x;
    hist[t] = 0; hist[t + 256] = 0;
    __syncthreads();

    int base = blockIdx.x * CH;
    int lim = E - base; if (lim > CH) lim = CH;

    for (int i = t; i < lim; i += 256)
        atomicAdd(&hist[dst[base + i] >> 8], 1);
    __syncthreads();

    int c0 = hist[t], c1 = hist[t + 256];
    for (int o = 1; o < 512; o <<= 1) {
        int v0 = (t >= o) ? hist[t - o] : 0;
        int v1 = hist[t + 256 - o];
        __syncthreads();
        hist[t] += v0;
        hist[t + 256] += v1;
        __syncthreads();
    }
    int e0 = hist[t] - c0;          // exclusive
    int e1 = hist[t + 256] - c1;
    cur[t] = e0; cur[t + 256] = e1;
    if (t < NBK)       off[t]       = blk_off[t * NB1 + blockIdx.x] - e0;
    if (t + 256 < NBK) off[t + 256] = blk_off[(t + 256) * NB1 + blockIdx.x] - e1;
    __syncthreads();

    for (int i = t; i < lim; i += 256) {
        int d = dst[base + i];
        int sv = src[base + i];
        int b = d >> 8;
        int slot = atomicAdd(&cur[b], 1);
        stage[slot] = ((unsigned int)sv << 8) | (unsigned int)(d & 255);
        bko[slot] = (unsigned short)b;
    }
    __syncthreads();

    for (int i = t; i < lim; i += 256) {
        int b = bko[i];
        part_arr[off[b] + i] = stage[i];
    }
}

__global__ __launch_bounds__(256) void k_sortfill(const unsigned int* __restrict__ part_arr,
                                                  const int* __restrict__ bkt_base,
                                                  int N, int E,
                                                  int* __restrict__ col,
                                                  int* __restrict__ rowptr,
                                                  float* __restrict__ inv_sqrt) {
    __shared__ unsigned int in_[CAP];
    __shared__ int outS[CAP];
    __shared__ int hist[256];
    __shared__ int scn[256];
    __shared__ int cur[256];

    int b = blockIdx.x;
    int base = bkt_base[b];
    int nb   = bkt_base[b + 1] - base;
    int t = threadIdx.x;

    hist[t] = 0;
    __syncthreads();

    for (int i = t; i < nb; i += 256) {
        unsigned int pk = part_arr[base + i];
        in_[i] = pk;
        atomicAdd(&hist[pk & 255u], 1);
    }
    __syncthreads();

    int cnt = hist[t];
    for (int o = 1; o < 256; o <<= 1) {
        int v = (t >= o) ? hist[t - o] : 0;
        __syncthreads();
        hist[t] += v;
        __syncthreads();
    }
    int excl = hist[t] - cnt;
    scn[t] = excl;
    cur[t] = 0;
    __syncthreads();

    for (int i = t; i < nb; i += 256) {
        unsigned int pk = in_[i];
        int d = (int)(pk & 255u);
        int r = atomicAdd(&cur[d], 1);
        outS[scn[d] + r] = (int)(pk >> 8);
    }
    __syncthreads();

    for (int i = t; i < nb; i += 256) col[base + i] = outS[i];

    int node = b * 256 + t;
    if (node < N) {
        rowptr[node] = base + excl;
        inv_sqrt[node] = rsqrtf((float)(cnt + 1));   // +1: self-loop
    }
    if (b == 0 && t == 0) rowptr[N] = E;
}

// ---------------- Register-tiled GEMM, f32 or bf16 input, bf16 output ----------------
// outg[n][c] = bf16( inv_sqrt[n] * sum_k in[n][k]*W[k][c] )

template <bool BF16IN>
__global__ __launch_bounds__(256, 3) void k_gemm_rt(const void* __restrict__ inp,
                          const float* __restrict__ W,
                          const float* __restrict__ inv_sqrt,
                          ushort_t* __restrict__ outg, int N) {
    __shared__ float xsT[32][132];
    __shared__ float ws[32][132];

    const int t = threadIdx.x;
    const int row0 = blockIdx.x * 128;
    const int lane = t & 63;
    const int wave = t >> 6;
    const int rg = ((wave >> 1) << 3) + (lane >> 3);  // 0..15 row group
    const int cg = ((wave & 1) << 3) + (lane & 7);    // 0..15 col group

    const float4* W4 = (const float4*)W;

    float4 acc[8][2];
    #pragma unroll
    for (int i = 0; i < 8; i++) {
        acc[i][0] = make_float4(0.f, 0.f, 0.f, 0.f);
        acc[i][1] = make_float4(0.f, 0.f, 0.f, 0.f);
    }

    const bool full = (row0 + 128 <= N);

    for (int kt = 0; kt < 4; kt++) {
        if (BF16IN) {
            const uint4* in16 = (const uint4*)inp;   // row = 16 uint4 (128 bf16)
            #pragma unroll
            for (int i = 0; i < 2; i++) {
                int idx = t + i * 256;      // 0..511
                int r  = idx >> 2;          // 0..127
                int c8 = idx & 3;           // uint4 within kt slice (8 bf16)
                int row = row0 + r;
                uint4 v = make_uint4(0u, 0u, 0u, 0u);
                if (full || row < N) v = in16[(size_t)row * 16 + kt * 4 + c8];
                int kb = c8 * 8;
                xsT[kb + 0][r] = bfl(v.x); xsT[kb + 1][r] = bfh(v.x);
                xsT[kb + 2][r] = bfl(v.y); xsT[kb + 3][r] = bfh(v.y);
                xsT[kb + 4][r] = bfl(v.z); xsT[kb + 5][r] = bfh(v.z);
                xsT[kb + 6][r] = bfl(v.w); xsT[kb + 7][r] = bfh(v.w);
            }
        } else {
            const float4* in4 = (const float4*)inp;
            #pragma unroll
            for (int i = 0; i < 4; i++) {
                int idx = t + i * 256;
                int r  = idx >> 3;
                int c4 = idx & 7;
                int row = row0 + r;
                float4 v = make_float4(0.f, 0.f, 0.f, 0.f);
                if (full || row < N) v = in4[(size_t)row * 32 + kt * 8 + c4];
                xsT[c4 * 4 + 0][r] = v.x;
                xsT[c4 * 4 + 1][r] = v.y;
                xsT[c4 * 4 + 2][r] = v.z;
                xsT[c4 * 4 + 3][r] = v.w;
            }
        }
        #pragma unroll
        for (int i = 0; i < 4; i++) {
            int idx = t + i * 256;
            int kk = idx >> 5;
            int c4 = idx & 31;
            *(float4*)&ws[kk][c4 * 4] = W4[(size_t)(kt * 32 + kk) * 32 + c4];
        }
        __syncthreads();

        #pragma unroll 8
        for (int k = 0; k < 32; k++) {
            float4 a0 = *(const float4*)&xsT[k][rg * 8];
            float4 a1 = *(const float4*)&xsT[k][rg * 8 + 4];
            float4 b0 = *(const float4*)&ws[k][cg * 8];
            float4 b1 = *(const float4*)&ws[k][cg * 8 + 4];
            float av[8] = {a0.x, a0.y, a0.z, a0.w, a1.x, a1.y, a1.z, a1.w};
            #pragma unroll
            for (int i = 0; i < 8; i++) {
                acc[i][0].x += av[i] * b0.x;
                acc[i][0].y += av[i] * b0.y;
                acc[i][0].z += av[i] * b0.z;
                acc[i][0].w += av[i] * b0.w;
                acc[i][1].x += av[i] * b1.x;
                acc[i][1].y += av[i] * b1.y;
                acc[i][1].z += av[i] * b1.z;
                acc[i][1].w += av[i] * b1.w;
            }
        }
        __syncthreads();
    }

    #pragma unroll
    for (int i = 0; i < 8; i++) {
        int row = row0 + rg * 8 + i;
        if (full || row < N) {
            float s = inv_sqrt[row];
            float4 o0 = acc[i][0], o1 = acc[i][1];
            uint4 pk;
            pk.x = (uint_t)f2bf(s * o0.x) | ((uint_t)f2bf(s * o0.y) << 16);
            pk.y = (uint_t)f2bf(s * o0.z) | ((uint_t)f2bf(s * o0.w) << 16);
            pk.z = (uint_t)f2bf(s * o1.x) | ((uint_t)f2bf(s * o1.y) << 16);
            pk.w = (uint_t)f2bf(s * o1.z) | ((uint_t)f2bf(s * o1.w) << 16);
            ((uint4*)(outg + (size_t)row * 128))[cg] = pk;
        }
    }
}

// ---------------- Aggregate layer 1 (bf16 gather -> bf16 h) ----------------
// h[n] = relu(inv_sqrt[n]*(sum g[col] + g[n]) + b), stored packed bf16

__global__ __launch_bounds__(256) void k_agg(const ushort_t* __restrict__ g,
                            const int* __restrict__ rowptr,
                            const int* __restrict__ col, const float* __restrict__ inv_sqrt,
                            const float* __restrict__ bias, ushort_t* __restrict__ outh, int N) {
    int wid  = (blockIdx.x * blockDim.x + threadIdx.x) >> 6;   // node
    int lane = threadIdx.x & 63;
    if (wid >= N) return;

    int start = rowptr[wid];
    int end   = rowptr[wid + 1];

    const uint_t* g1 = (const uint_t*)g;    // row = 64 uints (128 bf16)
    float accx = 0.f, accy = 0.f;

    for (int tt = start; tt < end; tt += 8) {
        int idx[8];
        #pragma unroll
        for (int i = 0; i < 8; i++)
            idx[i] = (tt + i < end) ? col[tt + i] : wid;
        uint_t v[8];
        #pragma unroll
        for (int i = 0; i < 8; i++)
            v[i] = g1[(size_t)((unsigned)idx[i] * 64u + (unsigned)lane)];
        #pragma unroll
        for (int i = 0; i < 8; i++) {
            if (tt + i < end) {
                accx += bfl(v[i]);
                accy += bfh(v[i]);
            }
        }
    }

    uint_t sv = g1[(unsigned)wid * 64u + (unsigned)lane];
    accx += bfl(sv);
    accy += bfh(sv);

    float is = inv_sqrt[wid];
    float2 b = ((const float2*)bias)[lane];
    float ox = fmaxf(fmaf(is, accx, b.x), 0.f);
    float oy = fmaxf(fmaf(is, accy, b.y), 0.f);
    uint_t pk = (uint_t)f2bf(ox) | ((uint_t)f2bf(oy) << 16);
    ((uint_t*)outh)[(size_t)wid * 64 + lane] = pk;
}

// ---------------- Aggregate layer 2 + fused mean-pool ----------------
// h2 row computed in registers, reduced per-block over sorted batch runs,
// atomically added into pooled/counts. h2 never hits HBM.
// 1024 threads = 16 waves = 16 nodes per block.

__global__ __launch_bounds__(1024) void k_agg_pool(const ushort_t* __restrict__ g,
                            const int* __restrict__ rowptr,
                            const int* __restrict__ col, const float* __restrict__ inv_sqrt,
                            const float* __restrict__ bias, const int* __restrict__ batch,
                            float* __restrict__ pooled, int* __restrict__ counts, int N) {
    __shared__ float hr[16][128];

    int w    = threadIdx.x >> 6;
    int lane = threadIdx.x & 63;
    int nb   = blockIdx.x * 16;
    int wid  = nb + w;
    bool valid = wid < N;

    int start = 0, end = 0;
    if (valid) { start = rowptr[wid]; end = rowptr[wid + 1]; }

    const uint_t* g1 = (const uint_t*)g;
    float accx = 0.f, accy = 0.f;

    for (int tt = start; tt < end; tt += 8) {
        int idx[8];
        #pragma unroll
        for (int i = 0; i < 8; i++)
            idx[i] = (tt + i < end) ? col[tt + i] : wid;
        uint_t v[8];
        #pragma unroll
        for (int i = 0; i < 8; i++)
            v[i] = g1[(size_t)((unsigned)idx[i] * 64u + (unsigned)lane)];
        #pragma unroll
        for (int i = 0; i < 8; i++) {
            if (tt + i < end) {
                accx += bfl(v[i]);
                accy += bfh(v[i]);
            }
        }
    }

    if (valid) {
        uint_t sv = g1[(unsigned)wid * 64u + (unsigned)lane];
        accx += bfl(sv);
        accy += bfh(sv);
        float is = inv_sqrt[wid];
        float2 b = ((const float2*)bias)[lane];
        float ox = fmaxf(fmaf(is, accx, b.x), 0.f);
        float oy = fmaxf(fmaf(is, accy, b.y), 0.f);
        ((float2*)&hr[w][0])[lane] = make_float2(ox, oy);
    }
    __syncthreads();

    int t = threadIdx.x;
    if (t < 128) {
        // per-feature reduction over this block's (sorted) batch runs
        float acc = 0.f;
        int bprev = -1;
        for (int w2 = 0; w2 < 16; w2++) {
            int n = nb + w2;
            if (n >= N) break;
            int bb = batch[n];
            if (bb != bprev) {
                if (bprev >= 0) atomicAdd(&pooled[(size_t)bprev * 128 + t], acc);
                acc = 0.f;
                bprev = bb;
            }
            acc += hr[w2][t];
        }
        if (bprev >= 0) atomicAdd(&pooled[(size_t)bprev * 128 + t], acc);
    } else if (t == 128) {
        int cnt = 0;
        int bprev = -1;
        for (int w2 = 0; w2 < 16; w2++) {
            int n = nb + w2;
            if (n >= N) break;
            int bb = batch[n];
            if (bb != bprev) {
                if (bprev >= 0) atomicAdd(&counts[bprev], cnt);
                cnt = 0;
                bprev = bb;
            }
            cnt++;
        }
        if (bprev >= 0) atomicAdd(&counts[bprev], cnt);
    }
}

// ---------------- MLP head ----------------

__global__ void k_mlp(const float* __restrict__ pooled, const int* __restrict__ counts,
                      const float* __restrict__ Wc1, const float* __restrict__ bc1,
                      const float* __restrict__ Wc2, const float* __restrict__ bc2,
                      float* __restrict__ out, int G) {
    int g = blockIdx.x;
    int j = threadIdx.x;    // 0..63
    __shared__ float pm[128];
    __shared__ float z[64];

    float invc = 1.0f / fmaxf((float)counts[g], 1.0f);
    pm[j]      = pooled[(size_t)g * 128 + j] * invc;
    pm[j + 64] = pooled[(size_t)g * 128 + 64 + j] * invc;
    __syncthreads();

    float a = bc1[j];
    #pragma unroll 8
    for (int k = 0; k < 128; k++) a += pm[k] * Wc1[k * 64 + j];
    z[j] = fmaxf(a, 0.f);
    __syncthreads();

    if (j < 8) {
        float o = bc2[j];
        #pragma unroll 8
        for (int k = 0; k < 64; k++) o += z[k] * Wc2[k * 8 + j];
        out[(size_t)g * 8 + j] = o;
    }
}

// ---------------- launch ----------------

extern "C" void kernel_launch(void* const* d_in, const int* in_sizes, int n_in,
                              void* d_out, int out_size, void* d_ws, size_t ws_size,
                              hipStream_t stream) {
    const float* x    = (const float*)d_in[0];
    const int*   ei   = (const int*)d_in[1];
    const int*   batch= (const int*)d_in[2];
    const float* W1   = (const float*)d_in[4];
    const float* b1   = (const float*)d_in[5];
    const float* W2   = (const float*)d_in[6];
    const float* b2   = (const float*)d_in[7];
    const float* Wc1  = (const float*)d_in[8];
    const float* bc1  = (const float*)d_in[9];
    const float* Wc2  = (const float*)d_in[10];
    const float* bc2  = (const float*)d_in[11];
    float* out = (float*)d_out;

    const int N = in_sizes[0] / 128;
    const int E = in_sizes[1] / 2;
    const int G = out_size / 8;

    const int* src = ei;
    const int* dst = ei + E;

    const int NBK = DIV_UP(N, 256);     // buckets of 256 nodes
    const int NB1 = DIV_UP(E, CH);      // partition blocks

    char* p = (char*)d_ws;
    auto alloc = [&](size_t bytes) {
        char* q = p;
        p += (bytes + 255) & ~(size_t)255;
        return q;
    };
    ushort_t* bufG1    = (ushort_t*)alloc((size_t)N * 128 * 2);  // g1 / g2 staging (bf16)
    ushort_t* bufG2    = (ushort_t*)alloc((size_t)N * 128 * 2);
    ushort_t* bufH     = (ushort_t*)alloc((size_t)N * 128 * 2);  // h1 (bf16)
    int*      rowptr   = (int*)     alloc(((size_t)N + 1) * 4);
    int*      colA     = (int*)     alloc((size_t)E * 4);
    float*    inv_sqrt = (float*)   alloc((size_t)N * 4);
    int*      blk_hist = (int*)     alloc((size_t)NBK * NB1 * 4);
    int*      blk_off  = (int*)     alloc((size_t)NBK * NB1 * 4);
    int*      bkt_base = (int*)     alloc(((size_t)NBK + 1) * 4);
    int*      bktT     = (int*)     alloc((size_t)NBK * 4);
    float*    pooled   = (float*)   alloc((size_t)G * 128 * 4);
    int*      counts   = (int*)     alloc((size_t)G * 4);

    // part_arr aliases bufG1: consumed by k_sortfill before GEMM1 writes bufG1
    unsigned int* part_arr = (unsigned int*)bufG1;

    hipMemsetAsync(pooled, 0, (size_t)G * 128 * 4, stream);
    hipMemsetAsync(counts, 0, (size_t)G * 4, stream);

    // CSR build (bucketed counting sort, parallel 3-level scan)
    k_hist1<<<NB1, 256, 0, stream>>>(dst, E, NBK, NB1, blk_hist);
    k_rowscan<<<NBK, 256, 0, stream>>>(blk_hist, blk_off, bktT, NB1);
    k_bktscan<<<1, 1024, 0, stream>>>(bktT, bkt_base, NBK, E);
    k_addbase<<<NBK, 256, 0, stream>>>(blk_off, bkt_base, NB1);
    k_scatter1<<<NB1, 256, 0, stream>>>(src, dst, E, NBK, NB1, blk_off, part_arr);
    k_sortfill<<<NBK, 256, 0, stream>>>(part_arr, bkt_base, N, E, colA, rowptr, inv_sqrt);

    // layer 1: GEMM (f32 in) -> g1 bf16 ; aggregate -> h1 bf16
    k_gemm_rt<false><<<DIV_UP(N, 128), 256, 0, stream>>>(x, W1, inv_sqrt, bufG1, N);
    k_agg<<<DIV_UP(N, 4), 256, 0, stream>>>(bufG1, rowptr, colA, inv_sqrt, b1, bufH, N);

    // layer 2: GEMM (bf16 in) -> g2 bf16 ; aggregate + fused pool
    k_gemm_rt<true><<<DIV_UP(N, 128), 256, 0, stream>>>(bufH, W2, inv_sqrt, bufG2, N);
    k_agg_pool<<<DIV_UP(N, 16), 1024, 0, stream>>>(bufG2, rowptr, colA, inv_sqrt, b2,
                                                   batch, pooled, counts, N);

    // head
    k_mlp<<<G, 64, 0, stream>>>(pooled, counts, Wc1, bc1, Wc2, bc2, out, G);
}